// Round 4
// baseline (211.276 us; speedup 1.0000x reference)
//
#include <hip/hip_runtime.h>
#include <math.h>

#define HID 512
#define PPB 32              // points per block (one 32-p MFMA tile)
// A-slab16: 32 p x 16 k, lane-linear, 512 halfs = 1 KB.
// A slabs: index s*32 + kstep (s = state, kstep = k/16). 128 KB total.
// W slabs: index jb32*32 + kstep (jb32 = j/32). 512 KB per layer.
// Lane-linear: element (idx31 = lane&31, k_local = (lane>>5)*8 + e) at
// halfs-offset lane*8 + e. One wave b128 access at lane*8 = contiguous
// 1 KB: conflict-free in LDS, coalesced in global.

typedef __attribute__((ext_vector_type(8)))  _Float16 half8;   // 4 VGPRs, MFMA frag
typedef __attribute__((ext_vector_type(4)))  _Float16 half4;
typedef __attribute__((ext_vector_type(4)))  float f32x4;
typedef __attribute__((ext_vector_type(16))) float f32x16;     // 32x32 acc

static __device__ __forceinline__ float fast_tanh(float x) {
    float e = __expf(2.f * x);
    return 1.f - 2.f / (e + 1.f);
}

// ---------------------------------------------------------------------------
// W prep: f32 (k,j) row-major -> f16 slab16s for the 32x32x16 A-operand.
// W slab (jb32, kstep): lane l holds W[k = kstep*16 + (l>>5)*8 + e]
//                                  [j = jb32*32 + (l&31)] at l*8+e.
// ---------------------------------------------------------------------------
__global__ __launch_bounds__(256) void prep_wt(
    const float* __restrict__ W1, const float* __restrict__ W2,
    _Float16* __restrict__ W1h, _Float16* __restrict__ W2h,
    unsigned* __restrict__ counter)
{
    if (blockIdx.x == 0 && threadIdx.x == 0) *counter = 0u;   // reset per replay
    __shared__ float T[64][65];
    int b = blockIdx.x;
    const float* W = (b < 64) ? W1 : W2;
    _Float16* Wh   = (b < 64) ? W1h : W2h;
    int tb = b & 63;
    int jbG = tb >> 3, kbG = tb & 7;
    int j0 = jbG * 64, k0 = kbG * 64;
    int t = threadIdx.x;
    #pragma unroll
    for (int r = 0; r < 16; ++r) {
        int kl = r * 4 + (t >> 6);
        int jl = t & 63;
        T[kl][jl] = W[(size_t)(k0 + kl) * HID + j0 + jl];   // coalesced
    }
    __syncthreads();
    int ol  = t & 63;                   // output lane
    int og  = t >> 6;                   // 0..3: (jb_l, ks_hi)
    int jb_l  = og >> 1;                // local 32-j group (0..1)
    int ks_hi = og & 1;
    #pragma unroll
    for (int lkb = 0; lkb < 2; ++lkb) {
        int kstep_l = ks_hi * 2 + lkb;  // local kstep (0..3)
        half8 v;
        #pragma unroll
        for (int e = 0; e < 8; ++e)
            v[e] = (_Float16)T[kstep_l * 16 + (ol >> 5) * 8 + e][jb_l * 32 + (ol & 31)];
        size_t out = (size_t)((jbG * 2 + jb_l) * 32 + kbG * 4 + kstep_l) * 512
                   + ol * 8;
        *(half8*)(Wh + out) = v;
    }
}

// ---------------------------------------------------------------------------
// One hidden-layer pass, 32x32x16 MFMA. Wave wv (of 16) owns j-range
// [32wv, 32wv+32) = one W slab column (32 ksteps). Per kstep: 1 W-frag
// (reused by 4 states) + 4 A-frags + 4 MFMA. acc = 4 x f32x16 = 64 AGPR.
// W ping-pong (depth 2) and A in-place depth-1 reload (R3-proven, no spill).
// ---------------------------------------------------------------------------
template<bool FULL>
static __device__ __forceinline__ void layer_pass(
    const _Float16* __restrict__ Wh, const float* __restrict__ bias,
    _Float16* Als, int wv, int lane)
{
    const int loff = lane * 8;
    const _Float16* Wp = Wh + (size_t)wv * 32 * 512;   // wave's 32 ksteps

    f32x16 acc[4];
    #pragma unroll
    for (int s = 0; s < 4; ++s) acc[s] = (f32x16)0.f;

    half8 wf0 = *(const half8*)(Wp + 0 * 512 + loff);
    half8 wf1 = *(const half8*)(Wp + 1 * 512 + loff);
    half8 a[4];
    #pragma unroll
    for (int s = 0; s < 4; ++s)
        a[s] = *(const half8*)(Als + (s * 32 + 0) * 512 + loff);

    auto step = [&](int i, half8& wreg) {
        #pragma unroll
        for (int s = 0; s < 4; ++s) {
            acc[s] = __builtin_amdgcn_mfma_f32_32x32x16_f16(wreg, a[s], acc[s], 0, 0, 0);
            // reload a[s] for kstep i+1 right after its use at i (WAR, in place)
            if (i < 31)
                a[s] = *(const half8*)(Als + (s * 32 + i + 1) * 512 + loff);
        }
        // reload this W reg for kstep i+2 (2-step slack over L2 latency)
        if (i < 30)
            wreg = *(const half8*)(Wp + (size_t)(i + 2) * 512 + loff);
    };

    #pragma unroll
    for (int i = 0; i < 32; i += 2) {
        step(i,     wf0);
        step(i + 1, wf1);
    }

    __syncthreads();   // all waves done reading Als; safe to overwrite

    // epilogue: D col = p = lane&31; row j = wv*32 + (reg&3) + 8*(reg>>2)
    //                                       + 4*(lane>>5), reg = g*4 + m.
    // Next-layer target: kstep' = 2wv + (g>>1); octet = g&1; e = m + 4*hi.
    const int p  = lane & 31;
    const int hi = lane >> 5;
    #pragma unroll
    for (int g = 0; g < 4; ++g) {
        const int jv  = wv * 32 + 8 * g + 4 * hi;    // j for m = 0
        const int kst = wv * 2 + (g >> 1);           // target kstep
        f32x4 bv = *(const f32x4*)&bias[jv];
        half4 vh, vt1, vt2, vS;
        #pragma unroll
        for (int m = 0; m < 4; ++m) {
            float a_ = fast_tanh(acc[0][g * 4 + m] + bv[m]);
            float gg = 1.f - a_ * a_;
            float z1 = acc[1][g * 4 + m];
            float z2 = acc[2][g * 4 + m];
            vh[m] = (_Float16)a_;
            if (FULL) {
                vt1[m] = (_Float16)(gg * z1);
                vt2[m] = (_Float16)(gg * z2);
            }
            vS[m] = (_Float16)(gg * acc[3][g * 4 + m] - 2.f * a_ * gg * (z1 * z1 + z2 * z2));
        }
        const int ooff = ((g & 1) * 32 + p) * 8 + 4 * hi;
        *(half4*)(Als + (0 * 32 + kst) * 512 + ooff) = vh;
        if (FULL) {
            *(half4*)(Als + (1 * 32 + kst) * 512 + ooff) = vt1;
            *(half4*)(Als + (2 * 32 + kst) * 512 + ooff) = vt2;
        }
        *(half4*)(Als + (3 * 32 + kst) * 512 + ooff) = vS;
    }
    __syncthreads();   // Als(next layer) complete
}

// ---------------------------------------------------------------------------
// Fused: layer0 init -> L1 -> L2 -> final dot + loss partials + grid reduce.
// 32 pts/block, 1024 threads (16 waves), 128 KB LDS -> 1 block/CU,
// 4 waves/SIMD. W panel read ONCE per 32 points (half of R3's L2 demand).
// ---------------------------------------------------------------------------
__global__ __launch_bounds__(1024, 4) void pois_fused(
    const float* __restrict__ x_int, const float* __restrict__ x_bnd,
    const float* __restrict__ W0, const float* __restrict__ b0,
    const _Float16* __restrict__ W1h, const float* __restrict__ b1,
    const _Float16* __restrict__ W2h, const float* __restrict__ b2,
    const float* __restrict__ W3, const float* __restrict__ b3,
    float* __restrict__ partials, unsigned* __restrict__ counter,
    float* __restrict__ out, int NI, int NT, int nblk)
{
    __shared__ _Float16 Als[4 * 32 * 512];   // 128 KB
    __shared__ float scU[16][32], scL[16][32], sc[64];
    __shared__ float ri[4], rb[4];
    __shared__ int lastFlag;

    const int tid = threadIdx.x;
    const int wv = tid >> 6, lane = tid & 63;
    const int p  = lane & 31;
    const int hi = lane >> 5;
    const int p0 = blockIdx.x * PPB;

    // ---- layer 0: wave wv fills ksteps 2wv, 2wv+1 for all 4 states ----
    {
        int gp = p0 + p;
        int gpc = (gp >= NT) ? 0 : gp;
        float xx, yy;
        if (gpc < NI) { xx = x_int[2 * gpc];        yy = x_int[2 * gpc + 1]; }
        else          { xx = x_bnd[2 * (gpc - NI)]; yy = x_bnd[2 * (gpc - NI) + 1]; }
        #pragma unroll
        for (int t = 0; t < 2; ++t) {
            const int kstep = wv * 2 + t;
            const int k = kstep * 16 + hi * 8;
            f32x4 w0a = *(const f32x4*)&W0[k],       w0b = *(const f32x4*)&W0[k + 4];
            f32x4 w1a = *(const f32x4*)&W0[HID + k], w1b = *(const f32x4*)&W0[HID + k + 4];
            f32x4 b0a = *(const f32x4*)&b0[k],       b0b = *(const f32x4*)&b0[k + 4];
            half8 vh, vt1, vt2, vS;
            #pragma unroll
            for (int e = 0; e < 8; ++e) {
                float w0i = (e < 4) ? w0a[e] : w0b[e - 4];
                float w1i = (e < 4) ? w1a[e] : w1b[e - 4];
                float bbi = (e < 4) ? b0a[e] : b0b[e - 4];
                float a = fast_tanh(xx * w0i + yy * w1i + bbi);
                float g = 1.f - a * a;
                vh[e]  = (_Float16)a;
                vt1[e] = (_Float16)(g * w0i);
                vt2[e] = (_Float16)(g * w1i);
                vS[e]  = (_Float16)(-2.f * a * g * (w0i * w0i + w1i * w1i));
            }
            const int off = lane * 8;
            *(half8*)(Als + (0 * 32 + kstep) * 512 + off) = vh;
            *(half8*)(Als + (1 * 32 + kstep) * 512 + off) = vt1;
            *(half8*)(Als + (2 * 32 + kstep) * 512 + off) = vt2;
            *(half8*)(Als + (3 * 32 + kstep) * 512 + off) = vS;
        }
    }
    __syncthreads();

    layer_pass<true >(W1h, b1, Als, wv, lane);
    layer_pass<false>(W2h, b2, Als, wv, lane);

    // ---- final: partial dots over this wave's ksteps (2wv, 2wv+1) ----
    {
        float u = 0.f, lap = 0.f;
        #pragma unroll
        for (int t = 0; t < 2; ++t) {
            const int kstep = wv * 2 + t;
            const int k = kstep * 16 + hi * 8;
            f32x4 wa = *(const f32x4*)&W3[k], wb = *(const f32x4*)&W3[k + 4];
            half8 hh = *(const half8*)(Als + (0 * 32 + kstep) * 512 + lane * 8);
            half8 ss = *(const half8*)(Als + (3 * 32 + kstep) * 512 + lane * 8);
            #pragma unroll
            for (int e = 0; e < 4; ++e) {
                u   += (float)hh[e] * wa[e] + (float)hh[e + 4] * wb[e];
                lap += (float)ss[e] * wa[e] + (float)ss[e + 4] * wb[e];
            }
        }
        // reduce over the two k-octet halves (lanes p and p+32)
        u   += __shfl_xor(u, 32);
        lap += __shfl_xor(lap, 32);
        if (lane < 32) { scU[wv][p] = u; scL[wv][p] = lap; }
    }
    __syncthreads();

    // per-point losses
    if (tid < 32) {
        const int pp = tid;
        float u = 0.f, lap = 0.f;
        #pragma unroll
        for (int w = 0; w < 16; ++w) { u += scU[w][pp]; lap += scL[w][pp]; }
        int gp = p0 + pp;
        float vi = 0.f, vb = 0.f;
        if (gp < NI) {
            const float PIf = 3.14159265358979323846f;
            float xx = x_int[2 * gp], yy = x_int[2 * gp + 1];
            float sx = sinf(PIf * xx);
            float y2 = yy * yy;
            float sy = sinf(PIf * y2), cy = cosf(PIf * y2);
            float f = -PIf * PIf * (1.f + 4.f * y2) * sx * sy + 2.f * PIf * sx * cy;
            float r = lap - f;
            vi = r * r;
        } else if (gp < NT) {
            float uu = u + b3[0];
            vb = uu * uu;
        }
        sc[pp * 2] = vi; sc[pp * 2 + 1] = vb;
    }
    __syncthreads();
    if (tid == 0) {
        float svi = 0.f, svb = 0.f;
        #pragma unroll
        for (int pp = 0; pp < PPB; ++pp) { svi += sc[pp * 2]; svb += sc[pp * 2 + 1]; }
        partials[blockIdx.x] = svi;
        partials[nblk + blockIdx.x] = svb;
        __threadfence();                              // release partials
        unsigned old = atomicAdd(counter, 1u);
        lastFlag = (old == (unsigned)(nblk - 1));
    }
    __syncthreads();

    // last arriving block: deterministic final reduction
    if (lastFlag) {
        __threadfence();                              // acquire partials
        if (tid < 256) {
            float si = 0.f, sb = 0.f;
            for (int i = tid; i < nblk; i += 256) {
                si += partials[i];
                sb += partials[nblk + i];
            }
            #pragma unroll
            for (int off = 32; off > 0; off >>= 1) {
                si += __shfl_xor(si, off);
                sb += __shfl_xor(sb, off);
            }
            int w = tid >> 6;
            if ((tid & 63) == 0) { ri[w] = si; rb[w] = sb; }
        }
    }
    __syncthreads();
    if (lastFlag && tid == 0) {
        float inter = (ri[0] + ri[1] + ri[2] + ri[3]) / (float)NI;
        float bound = (rb[0] + rb[1] + rb[2] + rb[3]) / (float)(NT - NI);
        out[0] = 0.01f * inter + bound;   // ALPHA = 0.01
        out[1] = inter;
        out[2] = bound;
    }
}

// ---------------------------------------------------------------------------
extern "C" void kernel_launch(void* const* d_in, const int* in_sizes, int n_in,
                              void* d_out, int out_size, void* d_ws, size_t ws_size,
                              hipStream_t stream)
{
    const float* x_int = (const float*)d_in[0];
    const float* x_bnd = (const float*)d_in[1];
    const float* W0 = (const float*)d_in[2];
    const float* b0 = (const float*)d_in[3];
    const float* W1 = (const float*)d_in[4];
    const float* b1 = (const float*)d_in[5];
    const float* W2 = (const float*)d_in[6];
    const float* b2 = (const float*)d_in[7];
    const float* W3 = (const float*)d_in[8];
    const float* b3 = (const float*)d_in[9];

    int NI = in_sizes[0] / 2;    // 20000
    int NB = in_sizes[1] / 2;    // 800
    int NT = NI + NB;            // 20800
    int nblk = (NT + PPB - 1) / PPB;   // 650
    (void)NB;

    // ws: [partials 8KB][counter @12KB][pad to 16KB][W1h 512KB][W2h 512KB]
    float* partials = (float*)d_ws;
    unsigned* counter = (unsigned*)((char*)d_ws + 12288);
    _Float16* W1h = (_Float16*)((char*)d_ws + 16384);
    _Float16* W2h = W1h + 262144;

    prep_wt<<<128, 256, 0, stream>>>(W1, W2, W1h, W2h, counter);

    pois_fused<<<nblk, 1024, 0, stream>>>(
        x_int, x_bnd, W0, b0, W1h, b1, W2h, b2, W3, b3,
        partials, counter, (float*)d_out, NI, NT, nblk);
}